// Round 5
// baseline (406.221 us; speedup 1.0000x reference)
//
#include <hip/hip_runtime.h>
#include <math.h>

#define EPS_BN 1e-5f

typedef __attribute__((ext_vector_type(8))) short bf16x8;
typedef __attribute__((ext_vector_type(4))) float f32x4;
typedef __attribute__((ext_vector_type(8))) _Float16 fp16x8;
typedef __attribute__((ext_vector_type(16))) float f32x16;

// ---------------------------------------------------------------------------
// async global->LDS, 16B per lane
// ---------------------------------------------------------------------------
__device__ __forceinline__ void gld_lds16(const void* g, void* l) {
    __builtin_amdgcn_global_load_lds(
        (const __attribute__((address_space(1))) unsigned int*)g,
        (__attribute__((address_space(3))) unsigned int*)l, 16, 0, 0);
}

__device__ __forceinline__ unsigned short f2bf(float f) {  // RNE fp32->bf16
    unsigned u = __float_as_uint(f);
    return (unsigned short)((u + 0x7FFFu + ((u >> 16) & 1u)) >> 16);
}

// Bit-exact fp32 distance vs np reference: sources pre-doubled so
// rn(tx*2sx) = 2*rn(tx*sx) exactly; d = rn(rn(sumT - dot2) + sumS).
__device__ __forceinline__ float dist_exact(float4 T, float4 s) {
    float dot2 = __fadd_rn(__fadd_rn(__fmul_rn(T.x, s.x), __fmul_rn(T.y, s.y)),
                           __fmul_rn(T.z, s.z));
    return __fadd_rn(__fsub_rn(T.w, dot2), s.w);
}

__device__ __forceinline__ float min3f(float a, float b, float c) {
    float d;
    asm("v_min3_f32 %0, %1, %2, %3" : "=v"(d) : "v"(a), "v"(b), "v"(c));
    return d;
}
__device__ __forceinline__ unsigned med3u(unsigned a, unsigned b, unsigned c) {
    unsigned d;
    asm("v_med3_u32 %0, %1, %2, %3" : "=v"(d) : "v"(a), "v"(b), "v"(c));
    return d;
}

// ---------------------------------------------------------------------------
// fp32 [M][K] -> bf16 tile-packed swizzled: granule rotation
// g=((k>>3)+(r>>1))&3 makes MFMA fragment ds_read_b128 2-lanes/bank (free).
// ---------------------------------------------------------------------------
__device__ __forceinline__ void conv_body(
    const float* __restrict__ src, unsigned short* __restrict__ dst,
    int blk, int tid, int K8log, int nslab)
{
    const int gid = blk * 256 + tid;
    const int m  = gid >> K8log;
    const int ko = gid & ((1 << K8log) - 1);
    const float4* s = (const float4*)src + ((size_t)m << (K8log + 1)) + ko * 2;
    float4 f0 = s[0];
    float4 f1 = s[1];
    const int mblk = m >> 7, r = m & 127;
    const int slab = ko >> 2, o = ko & 3;
    const int g = (o + (r >> 1)) & 3;
    unsigned short h[8] = {f2bf(f0.x), f2bf(f0.y), f2bf(f0.z), f2bf(f0.w),
                           f2bf(f1.x), f2bf(f1.y), f2bf(f1.z), f2bf(f1.w)};
    *(uint4*)(dst + ((size_t)(mblk * nslab + slab)) * 4096 + r * 32 + g * 8) =
        *(uint4*)h;
}

// ---------------------------------------------------------------------------
// One fused prep dispatch: bf16 pack A1/A2/W1/W2 + xyz packing.
//   sxyz1[i] = (2x, 2y, 2z, |s|^2)  (AoS, for exact tail re-select)
//   srcpk[i][16] f16: A-slots [hx,hx,lx, hy,hy,ly, hz,hz,lz, hw,lw, 0..]
//     built from NEGATED pre-doubled coords (-2x) hi/lo split + |s|^2 split
//   tgtpk[i][16] f16: B-slots [hx,lx,hx, hy,ly,hy, hz,lz,hz, 1,1, 0..]
//   txyz2[i] = (x, y, z, |t|^2)
//   => sum_k A_k*B_k ~= -2 t.s + |s|^2  (surrogate; Tw omitted: constant per
//      target, ordering-invariant). Verified on HW in the R2 round.
// ---------------------------------------------------------------------------
__global__ __launch_bounds__(256) void prep_all(
    const float* __restrict__ p1, const float* __restrict__ p2,
    const float* __restrict__ w1, const float* __restrict__ w2,
    unsigned short* __restrict__ A1p, unsigned short* __restrict__ A2p,
    unsigned short* __restrict__ W1p, unsigned short* __restrict__ W2p,
    const float* __restrict__ xyz1, const float* __restrict__ xyz2,
    float4* __restrict__ sxyz1, _Float16* __restrict__ srcpk,
    _Float16* __restrict__ tgtpk, float4* __restrict__ txyz2)
{
    const int blk = blockIdx.x, tid = threadIdx.x;
    if (blk < 4096)        conv_body(p1, A1p, blk,         tid, 6, 16);
    else if (blk < 12288)  conv_body(p2, A2p, blk - 4096,  tid, 5, 8);
    else if (blk < 12352)  conv_body(w1, W1p, blk - 12288, tid, 6, 16);
    else if (blk < 12384)  conv_body(w2, W2p, blk - 12352, tid, 5, 8);
    else if (blk < 12448) {                       // xyz1 pack: 16384 sources
        int i = (blk - 12384) * 256 + tid;
        float x = xyz1[i * 3 + 0], y = xyz1[i * 3 + 1], z = xyz1[i * 3 + 2];
        float ss = __fadd_rn(__fadd_rn(__fmul_rn(x, x), __fmul_rn(y, y)),
                             __fmul_rn(z, z));
        float x2 = x + x, y2 = y + y, z2 = z + z;
        sxyz1[i] = make_float4(x2, y2, z2, ss);
        float nx = -x2, ny = -y2, nz = -z2;
        _Float16 hx = (_Float16)nx, lx = (_Float16)(nx - (float)hx);
        _Float16 hy = (_Float16)ny, ly = (_Float16)(ny - (float)hy);
        _Float16 hz = (_Float16)nz, lz = (_Float16)(nz - (float)hz);
        _Float16 hw = (_Float16)ss, lw = (_Float16)(ss - (float)hw);
        _Float16 z0 = (_Float16)0.f;
        fp16x8 lo8 = {hx, hx, lx, hy, hy, ly, hz, hz};
        fp16x8 hi8 = {lz, hw, lw, z0, z0, z0, z0, z0};
        *(fp16x8*)(srcpk + (size_t)i * 16)     = lo8;
        *(fp16x8*)(srcpk + (size_t)i * 16 + 8) = hi8;
    } else {                                      // xyz2 pack: 65536 targets
        int i = (blk - 12448) * 256 + tid;
        float x = xyz2[i * 3 + 0], y = xyz2[i * 3 + 1], z = xyz2[i * 3 + 2];
        float st = __fadd_rn(__fadd_rn(__fmul_rn(x, x), __fmul_rn(y, y)),
                             __fmul_rn(z, z));
        txyz2[i] = make_float4(x, y, z, st);
        _Float16 hx = (_Float16)x, lx = (_Float16)(x - (float)hx);
        _Float16 hy = (_Float16)y, ly = (_Float16)(y - (float)hy);
        _Float16 hz = (_Float16)z, lz = (_Float16)(z - (float)hz);
        _Float16 z0 = (_Float16)0.f, one = (_Float16)1.0f;
        fp16x8 lo8 = {hx, lx, hx, hy, ly, hy, hz, lz};
        fp16x8 hi8 = {hz, one, one, z0, z0, z0, z0, z0};
        *(fp16x8*)(tgtpk + (size_t)i * 16)     = lo8;
        *(fp16x8*)(tgtpk + (size_t)i * 16 + 8) = hi8;
    }
}

// ---------------------------------------------------------------------------
// KNN phase 1: the R2 HW-VERIFIED knn_mfma wave flow, partitioned 4-way by
// restricting the block-loop range ONLY. Everything selection-related is
// verbatim R2: top-12 med3 sorted-insert, key = trunc25(flip(m)) |
// global_block_id(7b), 12-rank x 16-row exact stable tail over the full
// batch S, f64 (d-bits,idx) keys == lax.top_k semantics, shfl_xor(32)
// half merge. Deltas vs R2 (exactly three):
//   1) wave scans blocks [part*32, part*32+32) (part = blockIdx.x>>9);
//      blocks 0..511 replicate R2's grid for part 0, etc.
//   2) 3 f64 keys written to cand[tgt*12 + part*3] instead of w3/idx3.
//   3) knn_merge (R0/R1-verified) folds the 4 parts.
// Containment is strictly safer than the R2 config that passed: identical
// key precision and 12 tracked ranks, but 31 competitors instead of 127.
// ---------------------------------------------------------------------------
__global__ __launch_bounds__(256) void knn_part(
    const float4* __restrict__ sxyz1,
    const _Float16* __restrict__ srcpk,
    const _Float16* __restrict__ tgtpk,
    const float4* __restrict__ txyz2,
    double* __restrict__ cand)          // [65536][4 parts][3]
{
    const int tid  = threadIdx.x;
    const int wv   = tid >> 6;
    const int lane = tid & 63;
    const int col  = lane & 31;
    const int h    = lane >> 5;
    const int grp  = blockIdx.x & 511;   // R2's blockIdx role
    const int part = blockIdx.x >> 9;    // 0..3
    const int tgt  = grp * 128 + wv * 32 + col;
    const int batch = tgt >> 14;

    const float4 T = txyz2[tgt];
    const fp16x8 bfrag = *(const fp16x8*)(tgtpk + (size_t)tgt * 16 + h * 8);
    const _Float16* __restrict__ ap =
        srcpk + (size_t)batch * 65536 + (size_t)col * 16 + h * 8;
    const float4* __restrict__ S = sxyz1 + batch * 4096;

    const f32x16 zacc = {0.f,0.f,0.f,0.f, 0.f,0.f,0.f,0.f,
                         0.f,0.f,0.f,0.f, 0.f,0.f,0.f,0.f};

    unsigned k0 = 0xFFFFFFFFu, k1 = 0xFFFFFFFFu, k2 = 0xFFFFFFFFu,
             k3 = 0xFFFFFFFFu, k4 = 0xFFFFFFFFu, k5 = 0xFFFFFFFFu,
             k6 = 0xFFFFFFFFu, k7 = 0xFFFFFFFFu, k8 = 0xFFFFFFFFu,
             k9 = 0xFFFFFFFFu, k10 = 0xFFFFFFFFu, k11 = 0xFFFFFFFFu;

    const int b0 = part * 32;
    fp16x8 af = *(const fp16x8*)(ap + (size_t)b0 * 512);
#pragma unroll 4
    for (int b = b0; b < b0 + 32; b++) {
        fp16x8 afn = af;
        if (b < b0 + 31) afn = *(const fp16x8*)(ap + (size_t)(b + 1) * 512);
        f32x16 acc = __builtin_amdgcn_mfma_f32_32x32x16_f16(
            af, bfrag, zacc, 0, 0, 0);
        float m1 = min3f(acc[0], acc[1], acc[2]);
        float m2 = min3f(acc[3], acc[4], acc[5]);
        float m3 = min3f(acc[6], acc[7], acc[8]);
        float m4 = min3f(acc[9], acc[10], acc[11]);
        float m5 = min3f(acc[12], acc[13], acc[14]);
        float m6 = min3f(m1, m2, m3);
        float m7 = min3f(m4, m5, acc[15]);
        float m  = fminf(m6, m7);

        int fu = __float_as_int(m);
        unsigned fk = (unsigned)(fu ^ ((fu >> 31) | 0x80000000));
        unsigned key = (fk & 0xFFFFFF80u) | (unsigned)b;

        unsigned nk0 = key < k0 ? key : k0;
        k11 = med3u(key, k10, k11);
        k10 = med3u(key, k9, k10);
        k9  = med3u(key, k8, k9);
        k8  = med3u(key, k7, k8);
        k7  = med3u(key, k6, k7);
        k6  = med3u(key, k5, k6);
        k5  = med3u(key, k4, k5);
        k4  = med3u(key, k3, k4);
        k3  = med3u(key, k2, k3);
        k2  = med3u(key, k1, k2);
        k1  = med3u(key, k0, k1);
        k0  = nk0;
        af = afn;
    }

    // exact stable re-select over 12 half-blocks x 16 rows (this half)
    const double INITK = __hiloint2double(0x7F800000, 0);   // huge finite key
    double K0 = INITK, K1 = INITK, K2 = INITK;
#define INS3(kk) { if ((kk) < K2) {                                  \
        if ((kk) < K1) { K2 = K1;                                    \
            if ((kk) < K0) { K1 = K0; K0 = (kk); } else K1 = (kk);   \
        } else K2 = (kk); } }

#pragma unroll 1
    for (int r = 0; r < 12; r++) {
        const int bb = (int)(k0 & 127u);
        const float4* Sb = S + bb * 32 + 4 * h;
        const int sbase = bb * 32 + 4 * h;
#pragma unroll
        for (int e = 0; e < 16; e++) {
            const int row = (e & 3) + 8 * (e >> 2);
            float4 s = Sb[row];
            float d = dist_exact(T, s);
            double kk = __hiloint2double(__float_as_int(d), sbase + row);
            INS3(kk);
        }
        k0 = k1; k1 = k2; k2 = k3; k3 = k4; k4 = k5; k5 = k6;
        k6 = k7; k7 = k8; k8 = k9; k9 = k10; k10 = k11;
    }

    // merge lane-halves (each covered a disjoint half of this part's rows)
    double O0 = __shfl_xor(K0, 32);
    double O1 = __shfl_xor(K1, 32);
    double O2 = __shfl_xor(K2, 32);
    INS3(O0); INS3(O1); INS3(O2);
#undef INS3

    if (h == 0) {
        double* c = cand + (size_t)tgt * 12 + part * 3;
        c[0] = K0; c[1] = K1; c[2] = K2;
    }
}

// ---------------------------------------------------------------------------
// KNN phase 2: merge 4x3 candidate keys -> final top-3 + fp32 weights.
// (R0/R1 HW-verified pattern, 24->12 keys.)
// ---------------------------------------------------------------------------
__global__ __launch_bounds__(256) void knn_merge(
    const double* __restrict__ cand, float* __restrict__ w3,
    int* __restrict__ idx3)
{
    const int g = blockIdx.x * 256 + threadIdx.x;
    const double INIT = __hiloint2double(0x7F800000, 0);
    double k0 = INIT, k1 = INIT, k2 = INIT;
#pragma unroll
    for (int p = 0; p < 12; p++) {
        double k = cand[(size_t)g * 12 + p];
        if (k < k2) {
            if (k < k1) {
                k2 = k1;
                if (k < k0) { k1 = k0; k0 = k; }
                else        { k1 = k; }
            } else { k2 = k; }
        }
    }
    float d0 = __int_as_float(__double2hiint(k0));
    float d1 = __int_as_float(__double2hiint(k1));
    float d2 = __int_as_float(__double2hiint(k2));
    float w0 = 1.0f / __fadd_rn(d0, 1e-8f);
    float w1 = 1.0f / __fadd_rn(d1, 1e-8f);
    float w2 = 1.0f / __fadd_rn(d2, 1e-8f);
    float ws = __fadd_rn(__fadd_rn(w0, w1), w2);
    w3[(size_t)g * 3 + 0] = w0 / ws;
    w3[(size_t)g * 3 + 1] = w1 / ws;
    w3[(size_t)g * 3 + 2] = w2 / ws;
    idx3[(size_t)g * 3 + 0] = __double2loint(k0);
    idx3[(size_t)g * 3 + 1] = __double2loint(k1);
    idx3[(size_t)g * 3 + 2] = __double2loint(k2);
}

// ---------------------------------------------------------------------------
// bf16 MFMA GEMM + BN + ReLU (verified). Used for feats1.
// ---------------------------------------------------------------------------
__global__ __launch_bounds__(256) void gemm_bf16_bn_relu(
    const unsigned short* __restrict__ Ap,
    const unsigned short* __restrict__ Bp,
    const float* __restrict__ bias,
    const float* __restrict__ gamma,
    const float* __restrict__ beta,
    const float* __restrict__ mean,
    const float* __restrict__ var,
    float* __restrict__ out, int M, int K)
{
    __shared__ __align__(16) unsigned short As[4096];
    __shared__ __align__(16) unsigned short Bs[4096];

    const int tid  = threadIdx.x;
    const int w    = tid >> 6;
    const int lane = tid & 63;
    const int q    = lane >> 4;
    const int rl   = lane & 15;
    const int wm   = w >> 1, wn = w & 1;
    const int bn   = blockIdx.x, bm = blockIdx.y;
    const int nslab = K >> 5;

    f32x4 acc[4][4];
#pragma unroll
    for (int i = 0; i < 4; i++)
#pragma unroll
        for (int j = 0; j < 4; j++) acc[i][j] = (f32x4){0.f, 0.f, 0.f, 0.f};

    const unsigned short* Ab = Ap + (size_t)bm * nslab * 4096;
    const unsigned short* Bb = Bp + (size_t)bn * nslab * 4096;
    const int c0 = 2 * w;
    const int l8 = lane * 8;

    int aidx[4], bidx[4];
#pragma unroll
    for (int i = 0; i < 4; i++) {
        int rr = wm * 64 + i * 16 + rl;
        aidx[i] = rr * 32 + ((q + (rr >> 1)) & 3) * 8;
        int nn = wn * 64 + i * 16 + rl;
        bidx[i] = nn * 32 + ((q + (nn >> 1)) & 3) * 8;
    }

    for (int s = 0; s < nslab; s++) {
        __syncthreads();
        const unsigned short* a = Ab + (size_t)s * 4096;
        const unsigned short* b = Bb + (size_t)s * 4096;
        gld_lds16(a + (c0 + 0) * 512 + l8, &As[(c0 + 0) * 512 + l8]);
        gld_lds16(a + (c0 + 1) * 512 + l8, &As[(c0 + 1) * 512 + l8]);
        gld_lds16(b + (c0 + 0) * 512 + l8, &Bs[(c0 + 0) * 512 + l8]);
        gld_lds16(b + (c0 + 1) * 512 + l8, &Bs[(c0 + 1) * 512 + l8]);
        __syncthreads();

        bf16x8 af[4], bf[4];
#pragma unroll
        for (int i = 0; i < 4; i++) af[i] = *(const bf16x8*)&As[aidx[i]];
#pragma unroll
        for (int j = 0; j < 4; j++) bf[j] = *(const bf16x8*)&Bs[bidx[j]];
#pragma unroll
        for (int i = 0; i < 4; i++)
#pragma unroll
            for (int j = 0; j < 4; j++)
                acc[i][j] = __builtin_amdgcn_mfma_f32_16x16x32_bf16(
                    af[i], bf[j], acc[i][j], 0, 0, 0);
    }

    const int gm0 = bm * 128 + wm * 64;
    const int gn0 = bn * 128 + wn * 64;
#pragma unroll
    for (int j = 0; j < 4; j++) {
        int n = gn0 + j * 16 + rl;
        float sc = gamma[n] / sqrtf(var[n] + EPS_BN);
        float sh = beta[n] + (bias[n] - mean[n]) * sc;
#pragma unroll
        for (int i = 0; i < 4; i++) {
            int m0 = gm0 + i * 16 + q * 4;
#pragma unroll
            for (int t = 0; t < 4; t++) {
                float v = fmaxf(acc[i][j][t] * sc + sh, 0.f);
                out[(size_t)(m0 + t) * 256 + n] = v;
            }
        }
    }
}

// ---------------------------------------------------------------------------
// GEMM2 + BN + ReLU + fused 3-NN interpolation add:
//   out[m][n] = relu(BN(A2@W2^T)) + sum_k w3[m][k] * feats1[b(m), idx3[m][k]][n]
// ---------------------------------------------------------------------------
__global__ __launch_bounds__(256) void gemm2_interp(
    const unsigned short* __restrict__ Ap,
    const unsigned short* __restrict__ Bp,
    const float* __restrict__ bias,
    const float* __restrict__ gamma,
    const float* __restrict__ beta,
    const float* __restrict__ mean,
    const float* __restrict__ var,
    const float* __restrict__ feats1,   // [4*4096][256]
    const float* __restrict__ w3,       // [65536][3]
    const int*   __restrict__ idx3,     // [65536][3] (within-batch indices)
    float* __restrict__ out)
{
    __shared__ __align__(16) unsigned short As[4096];
    __shared__ __align__(16) unsigned short Bs[4096];

    const int tid  = threadIdx.x;
    const int w    = tid >> 6;
    const int lane = tid & 63;
    const int q    = lane >> 4;
    const int rl   = lane & 15;
    const int wm   = w >> 1, wn = w & 1;
    const int bn   = blockIdx.x, bm = blockIdx.y;
    const int nslab = 8;                 // K = 256

    f32x4 acc[4][4];
#pragma unroll
    for (int i = 0; i < 4; i++)
#pragma unroll
        for (int j = 0; j < 4; j++) acc[i][j] = (f32x4){0.f, 0.f, 0.f, 0.f};

    const unsigned short* Ab = Ap + (size_t)bm * nslab * 4096;
    const unsigned short* Bb = Bp + (size_t)bn * nslab * 4096;
    const int c0 = 2 * w;
    const int l8 = lane * 8;

    int aidx[4], bidx[4];
#pragma unroll
    for (int i = 0; i < 4; i++) {
        int rr = wm * 64 + i * 16 + rl;
        aidx[i] = rr * 32 + ((q + (rr >> 1)) & 3) * 8;
        int nn = wn * 64 + i * 16 + rl;
        bidx[i] = nn * 32 + ((q + (nn >> 1)) & 3) * 8;
    }

    for (int s = 0; s < nslab; s++) {
        __syncthreads();
        const unsigned short* a = Ab + (size_t)s * 4096;
        const unsigned short* b = Bb + (size_t)s * 4096;
        gld_lds16(a + (c0 + 0) * 512 + l8, &As[(c0 + 0) * 512 + l8]);
        gld_lds16(a + (c0 + 1) * 512 + l8, &As[(c0 + 1) * 512 + l8]);
        gld_lds16(b + (c0 + 0) * 512 + l8, &Bs[(c0 + 0) * 512 + l8]);
        gld_lds16(b + (c0 + 1) * 512 + l8, &Bs[(c0 + 1) * 512 + l8]);
        __syncthreads();

        bf16x8 af[4], bf[4];
#pragma unroll
        for (int i = 0; i < 4; i++) af[i] = *(const bf16x8*)&As[aidx[i]];
#pragma unroll
        for (int j = 0; j < 4; j++) bf[j] = *(const bf16x8*)&Bs[bidx[j]];
#pragma unroll
        for (int i = 0; i < 4; i++)
#pragma unroll
            for (int j = 0; j < 4; j++)
                acc[i][j] = __builtin_amdgcn_mfma_f32_16x16x32_bf16(
                    af[i], bf[j], acc[i][j], 0, 0, 0);
    }

    const int gm0 = bm * 128 + wm * 64;
    const int gn0 = bn * 128 + wn * 64;
    float scj[4], shj[4];
    int nj[4];
#pragma unroll
    for (int j = 0; j < 4; j++) {
        int n = gn0 + j * 16 + rl;
        nj[j] = n;
        float sc = gamma[n] / sqrtf(var[n] + EPS_BN);
        scj[j] = sc;
        shj[j] = beta[n] + (bias[n] - mean[n]) * sc;
    }

#pragma unroll
    for (int i = 0; i < 4; i++) {
#pragma unroll
        for (int t = 0; t < 4; t++) {
            const int m = gm0 + i * 16 + q * 4 + t;      // global target row
            const int bb = m >> 14;                      // batch
            const int j0 = idx3[(size_t)m * 3 + 0];
            const int j1 = idx3[(size_t)m * 3 + 1];
            const int j2 = idx3[(size_t)m * 3 + 2];
            const float u0 = w3[(size_t)m * 3 + 0];
            const float u1 = w3[(size_t)m * 3 + 1];
            const float u2 = w3[(size_t)m * 3 + 2];
            const float* f0 = feats1 + ((size_t)(bb * 4096 + j0)) * 256;
            const float* f1 = feats1 + ((size_t)(bb * 4096 + j1)) * 256;
            const float* f2 = feats1 + ((size_t)(bb * 4096 + j2)) * 256;
#pragma unroll
            for (int j = 0; j < 4; j++) {
                const int n = nj[j];
                float v = fmaxf(acc[i][j][t] * scj[j] + shj[j], 0.f);
                v += u0 * f0[n] + u1 * f1[n] + u2 * f2[n];
                out[(size_t)m * 256 + n] = v;
            }
        }
    }
}

extern "C" void kernel_launch(void* const* d_in, const int* in_sizes, int n_in,
                              void* d_out, int out_size, void* d_ws, size_t ws_size,
                              hipStream_t stream) {
    const float* xyz1    = (const float*)d_in[0];
    const float* points1 = (const float*)d_in[1];
    const float* xyz2    = (const float*)d_in[2];
    const float* points2 = (const float*)d_in[3];
    const float* W1  = (const float*)d_in[4];
    const float* b1  = (const float*)d_in[5];
    const float* g1  = (const float*)d_in[6];
    const float* be1 = (const float*)d_in[7];
    const float* m1  = (const float*)d_in[8];
    const float* v1  = (const float*)d_in[9];
    const float* W2  = (const float*)d_in[10];
    const float* b2  = (const float*)d_in[11];
    const float* g2  = (const float*)d_in[12];
    const float* be2 = (const float*)d_in[13];
    const float* m2  = (const float*)d_in[14];
    const float* v2  = (const float*)d_in[15];

    const size_t MB = 1u << 20;
    char* ws = (char*)d_ws;
    // srcpk/tgtpk/cand live in [0,16)MB, dead before gemm1 writes feats1.
    float*          feats1 = (float*)(ws);                       // 16 MB
    _Float16*       srcpk  = (_Float16*)(ws);                    // 512 KB
    _Float16*       tgtpk  = (_Float16*)(ws + 1 * MB);           // 2 MB
    double*         cand   = (double*)(ws + 4 * MB);             // 6 MB
    unsigned short* A1p    = (unsigned short*)(ws + 16 * MB);    // 16 MB
    unsigned short* A2p    = (unsigned short*)(ws + 32 * MB);    // 32 MB
    unsigned short* W1p    = (unsigned short*)(ws + 64 * MB);    // 0.5 MB
    unsigned short* W2p    = (unsigned short*)(ws + 64 * MB + 512 * 1024);
    float4*         sxyz1  = (float4*)(ws + 65 * MB);            // 256 KB
    float4*         txyz2  = (float4*)(ws + 66 * MB);            // 1 MB
    float*          w3     = (float*)(ws + 67 * MB);             // 0.75 MB
    int*            idx3   = (int*)(ws + 68 * MB);               // 0.75 MB
    float* outp = (float*)d_out;

    dim3 blk(256);
    // 1) all packing/conversion in one dispatch
    prep_all<<<12704, blk, 0, stream>>>(points1, points2, W1, W2,
                                        A1p, A2p, W1p, W2p,
                                        xyz1, xyz2, sxyz1, srcpk, tgtpk, txyz2);
    // 2) neighbor selection: R2-verified flow, 4-way block-range partition
    knn_part<<<2048, blk, 0, stream>>>(sxyz1, srcpk, tgtpk, txyz2, cand);
    // 3) fold 4 parts -> w3/idx3
    knn_merge<<<256, blk, 0, stream>>>(cand, w3, idx3);
    // 4) feats1 = relu(BN(points1 @ W1^T))  (clobbers srcpk/tgtpk/cand — dead)
    gemm_bf16_bn_relu<<<dim3(2, 128), blk, 0, stream>>>(A1p, W1p, b1, g1, be1, m1, v1,
                                                        feats1, 16384, 512);
    // 5) out = relu(BN(points2 @ W2^T)) + interp3(xyz2 <- xyz1, feats1)
    gemm2_interp<<<dim3(2, 512), blk, 0, stream>>>(A2p, W2p, b2, g2, be2, m2, v2,
                                                   feats1, w3, idx3, outp);
}

// Round 6
// 297.042 us; speedup vs baseline: 1.3676x; 1.3676x over previous
//
#include <hip/hip_runtime.h>
#include <math.h>

#define EPS_BN 1e-5f

typedef __attribute__((ext_vector_type(8))) short bf16x8;
typedef __attribute__((ext_vector_type(4))) float f32x4;
typedef __attribute__((ext_vector_type(8))) _Float16 fp16x8;
typedef __attribute__((ext_vector_type(16))) float f32x16;

// ---------------------------------------------------------------------------
// async global->LDS, 16B per lane
// ---------------------------------------------------------------------------
__device__ __forceinline__ void gld_lds16(const void* g, void* l) {
    __builtin_amdgcn_global_load_lds(
        (const __attribute__((address_space(1))) unsigned int*)g,
        (__attribute__((address_space(3))) unsigned int*)l, 16, 0, 0);
}

__device__ __forceinline__ unsigned short f2bf(float f) {  // RNE fp32->bf16
    unsigned u = __float_as_uint(f);
    return (unsigned short)((u + 0x7FFFu + ((u >> 16) & 1u)) >> 16);
}

// Bit-exact fp32 distance vs np reference: sources pre-doubled so
// rn(tx*2sx) = 2*rn(tx*sx) exactly; d = rn(rn(sumT - dot2) + sumS).
__device__ __forceinline__ float dist_exact(float4 T, float4 s) {
    float dot2 = __fadd_rn(__fadd_rn(__fmul_rn(T.x, s.x), __fmul_rn(T.y, s.y)),
                           __fmul_rn(T.z, s.z));
    return __fadd_rn(__fsub_rn(T.w, dot2), s.w);
}

__device__ __forceinline__ float min3f(float a, float b, float c) {
    float d;
    asm("v_min3_f32 %0, %1, %2, %3" : "=v"(d) : "v"(a), "v"(b), "v"(c));
    return d;
}
__device__ __forceinline__ unsigned med3u(unsigned a, unsigned b, unsigned c) {
    unsigned d;
    asm("v_med3_u32 %0, %1, %2, %3" : "=v"(d) : "v"(a), "v"(b), "v"(c));
    return d;
}

// ---------------------------------------------------------------------------
// fp32 [M][K] -> bf16 tile-packed swizzled: granule rotation
// g=((k>>3)+(r>>1))&3 makes MFMA fragment ds_read_b128 2-lanes/bank (free).
// ---------------------------------------------------------------------------
__device__ __forceinline__ void conv_body(
    const float* __restrict__ src, unsigned short* __restrict__ dst,
    int blk, int tid, int K8log, int nslab)
{
    const int gid = blk * 256 + tid;
    const int m  = gid >> K8log;
    const int ko = gid & ((1 << K8log) - 1);
    const float4* s = (const float4*)src + ((size_t)m << (K8log + 1)) + ko * 2;
    float4 f0 = s[0];
    float4 f1 = s[1];
    const int mblk = m >> 7, r = m & 127;
    const int slab = ko >> 2, o = ko & 3;
    const int g = (o + (r >> 1)) & 3;
    unsigned short h[8] = {f2bf(f0.x), f2bf(f0.y), f2bf(f0.z), f2bf(f0.w),
                           f2bf(f1.x), f2bf(f1.y), f2bf(f1.z), f2bf(f1.w)};
    *(uint4*)(dst + ((size_t)(mblk * nslab + slab)) * 4096 + r * 32 + g * 8) =
        *(uint4*)h;
}

// ---------------------------------------------------------------------------
// One fused prep dispatch: bf16 pack A1/A2/W1/W2 + xyz packing.
//   sxyz1[i] = (2x, 2y, 2z, |s|^2)  (AoS, for exact tail re-select)
//   srcpk[i][16] f16: A-slots [hx,hx,lx, hy,hy,ly, hz,hz,lz, hw,lw, 0..]
//     built from NEGATED pre-doubled coords (-2x) hi/lo split + |s|^2 split
//   tgtpk[i][16] f16: B-slots [hx,lx,hx, hy,ly,hy, hz,lz,hz, 1,1, 0..]
//   txyz2[i] = (x, y, z, |t|^2)
//   => sum_k A_k*B_k ~= -2 t.s + |s|^2  (surrogate; Tw omitted: constant per
//      target, ordering-invariant). Verified on HW in the R2/R5 rounds.
// ---------------------------------------------------------------------------
__global__ __launch_bounds__(256) void prep_all(
    const float* __restrict__ p1, const float* __restrict__ p2,
    const float* __restrict__ w1, const float* __restrict__ w2,
    unsigned short* __restrict__ A1p, unsigned short* __restrict__ A2p,
    unsigned short* __restrict__ W1p, unsigned short* __restrict__ W2p,
    const float* __restrict__ xyz1, const float* __restrict__ xyz2,
    float4* __restrict__ sxyz1, _Float16* __restrict__ srcpk,
    _Float16* __restrict__ tgtpk, float4* __restrict__ txyz2)
{
    const int blk = blockIdx.x, tid = threadIdx.x;
    if (blk < 4096)        conv_body(p1, A1p, blk,         tid, 6, 16);
    else if (blk < 12288)  conv_body(p2, A2p, blk - 4096,  tid, 5, 8);
    else if (blk < 12352)  conv_body(w1, W1p, blk - 12288, tid, 6, 16);
    else if (blk < 12384)  conv_body(w2, W2p, blk - 12352, tid, 5, 8);
    else if (blk < 12448) {                       // xyz1 pack: 16384 sources
        int i = (blk - 12384) * 256 + tid;
        float x = xyz1[i * 3 + 0], y = xyz1[i * 3 + 1], z = xyz1[i * 3 + 2];
        float ss = __fadd_rn(__fadd_rn(__fmul_rn(x, x), __fmul_rn(y, y)),
                             __fmul_rn(z, z));
        float x2 = x + x, y2 = y + y, z2 = z + z;
        sxyz1[i] = make_float4(x2, y2, z2, ss);
        float nx = -x2, ny = -y2, nz = -z2;
        _Float16 hx = (_Float16)nx, lx = (_Float16)(nx - (float)hx);
        _Float16 hy = (_Float16)ny, ly = (_Float16)(ny - (float)hy);
        _Float16 hz = (_Float16)nz, lz = (_Float16)(nz - (float)hz);
        _Float16 hw = (_Float16)ss, lw = (_Float16)(ss - (float)hw);
        _Float16 z0 = (_Float16)0.f;
        fp16x8 lo8 = {hx, hx, lx, hy, hy, ly, hz, hz};
        fp16x8 hi8 = {lz, hw, lw, z0, z0, z0, z0, z0};
        *(fp16x8*)(srcpk + (size_t)i * 16)     = lo8;
        *(fp16x8*)(srcpk + (size_t)i * 16 + 8) = hi8;
    } else {                                      // xyz2 pack: 65536 targets
        int i = (blk - 12448) * 256 + tid;
        float x = xyz2[i * 3 + 0], y = xyz2[i * 3 + 1], z = xyz2[i * 3 + 2];
        float st = __fadd_rn(__fadd_rn(__fmul_rn(x, x), __fmul_rn(y, y)),
                             __fmul_rn(z, z));
        txyz2[i] = make_float4(x, y, z, st);
        _Float16 hx = (_Float16)x, lx = (_Float16)(x - (float)hx);
        _Float16 hy = (_Float16)y, ly = (_Float16)(y - (float)hy);
        _Float16 hz = (_Float16)z, lz = (_Float16)(z - (float)hz);
        _Float16 z0 = (_Float16)0.f, one = (_Float16)1.0f;
        fp16x8 lo8 = {hx, lx, hx, hy, ly, hy, hz, lz};
        fp16x8 hi8 = {hz, one, one, z0, z0, z0, z0, z0};
        *(fp16x8*)(tgtpk + (size_t)i * 16)     = lo8;
        *(fp16x8*)(tgtpk + (size_t)i * 16 + 8) = hi8;
    }
}

// ---------------------------------------------------------------------------
// KNN fused: 4 waves x 32 targets per block; wave wv scans source blocks
// [32wv, 32wv+32) with the R2/R5-VERBATIM machinery (same MFMA surrogate,
// same key = trunc25(flip(m)) | global_block_id(7b), same 12-deep med3
// sorted-insert). Per (col,h) the 4 part-top-12 lists go through LDS and
// each wave takes top-12 of the union -- PROVABLY equal to R2's
// top-12-of-128 (any global top-12 key is inside its part's top-12).
// Wave wv exact-tails ranks [3wv, 3wv+3) (R5-verbatim tail body, global
// block ids, f64 (d-bits,idx) stable keys), shfl_xor(32) merges halves,
// LDS merges the 4 waves' partial top-3 -> weights + idx3 directly.
// Examined candidate set is bit-identical to R2's passing kernel; the
// split only redistributes the same work across waves.
// (R3's failure was a tail row-decode bug -- rows overflowed the 32-row
// block; here h stays lane-local and ids are pure block ids, as in R2/R5.)
// ---------------------------------------------------------------------------
__global__ __launch_bounds__(256) void knn_fused(
    const float4* __restrict__ sxyz1,
    const _Float16* __restrict__ srcpk,
    const _Float16* __restrict__ tgtpk,
    const float4* __restrict__ txyz2,
    float* __restrict__ w3, int* __restrict__ idx3)
{
    // keys: region r = h*32+col, stride 49 words -> col*17 mod 32 bijective
    // (2-way h-alias only = free). tails: stride 13 doubles -> 2-way.
    __shared__ unsigned keys_lds[64 * 49];
    __shared__ double   tails_lds[32 * 13];

    const int tid  = threadIdx.x;
    const int wv   = tid >> 6;          // source part 0..3
    const int lane = tid & 63;
    const int col  = lane & 31;         // target column
    const int h    = lane >> 5;         // source row half
    const int tgtg = blockIdx.x;        // 0..2047
    const int tgt  = tgtg * 32 + col;
    const int batch = tgt >> 14;

    const float4 T = txyz2[tgt];
    const fp16x8 bfrag = *(const fp16x8*)(tgtpk + (size_t)tgt * 16 + h * 8);
    const _Float16* __restrict__ ap =
        srcpk + (size_t)batch * 65536 + (size_t)col * 16 + h * 8;
    const float4* __restrict__ S = sxyz1 + batch * 4096;

    const f32x16 zacc = {0.f,0.f,0.f,0.f, 0.f,0.f,0.f,0.f,
                         0.f,0.f,0.f,0.f, 0.f,0.f,0.f,0.f};

    // -------- Phase A: scan part wv (R2/R5-verbatim key machinery) --------
    unsigned k0 = 0xFFFFFFFFu, k1 = 0xFFFFFFFFu, k2 = 0xFFFFFFFFu,
             k3 = 0xFFFFFFFFu, k4 = 0xFFFFFFFFu, k5 = 0xFFFFFFFFu,
             k6 = 0xFFFFFFFFu, k7 = 0xFFFFFFFFu, k8 = 0xFFFFFFFFu,
             k9 = 0xFFFFFFFFu, k10 = 0xFFFFFFFFu, k11 = 0xFFFFFFFFu;

    const int b0 = wv * 32;
    fp16x8 af = *(const fp16x8*)(ap + (size_t)b0 * 512);
#pragma unroll 4
    for (int b = b0; b < b0 + 32; b++) {
        fp16x8 afn = af;
        if (b < b0 + 31) afn = *(const fp16x8*)(ap + (size_t)(b + 1) * 512);
        f32x16 acc = __builtin_amdgcn_mfma_f32_32x32x16_f16(
            af, bfrag, zacc, 0, 0, 0);
        float m1 = min3f(acc[0], acc[1], acc[2]);
        float m2 = min3f(acc[3], acc[4], acc[5]);
        float m3 = min3f(acc[6], acc[7], acc[8]);
        float m4 = min3f(acc[9], acc[10], acc[11]);
        float m5 = min3f(acc[12], acc[13], acc[14]);
        float m6 = min3f(m1, m2, m3);
        float m7 = min3f(m4, m5, acc[15]);
        float m  = fminf(m6, m7);

        int fu = __float_as_int(m);
        unsigned fk = (unsigned)(fu ^ ((fu >> 31) | 0x80000000));
        unsigned key = (fk & 0xFFFFFF80u) | (unsigned)b;

        unsigned nk0 = key < k0 ? key : k0;
        k11 = med3u(key, k10, k11);
        k10 = med3u(key, k9, k10);
        k9  = med3u(key, k8, k9);
        k8  = med3u(key, k7, k8);
        k7  = med3u(key, k6, k7);
        k6  = med3u(key, k5, k6);
        k5  = med3u(key, k4, k5);
        k4  = med3u(key, k3, k4);
        k3  = med3u(key, k2, k3);
        k2  = med3u(key, k1, k2);
        k1  = med3u(key, k0, k1);
        k0  = nk0;
        af = afn;
    }

    {
        unsigned* kw = &keys_lds[(h * 32 + col) * 49 + wv * 12];
        kw[0] = k0;  kw[1] = k1;  kw[2] = k2;  kw[3] = k3;
        kw[4] = k4;  kw[5] = k5;  kw[6] = k6;  kw[7] = k7;
        kw[8] = k8;  kw[9] = k9;  kw[10] = k10; kw[11] = k11;
    }
    __syncthreads();

    // -------- Phase B: top-12 of union(4 x part-top-12) == R2's top-12 ----
    unsigned s0 = 0xFFFFFFFFu, s1 = 0xFFFFFFFFu, s2 = 0xFFFFFFFFu,
             s3 = 0xFFFFFFFFu, s4 = 0xFFFFFFFFu, s5 = 0xFFFFFFFFu,
             s6 = 0xFFFFFFFFu, s7 = 0xFFFFFFFFu, s8 = 0xFFFFFFFFu,
             s9 = 0xFFFFFFFFu, s10 = 0xFFFFFFFFu, s11 = 0xFFFFFFFFu;
#define INSK(key) {                                                   \
        unsigned n0 = (key) < s0 ? (key) : s0;                        \
        s11 = med3u((key), s10, s11);                                 \
        s10 = med3u((key), s9, s10);                                  \
        s9  = med3u((key), s8, s9);                                   \
        s8  = med3u((key), s7, s8);                                   \
        s7  = med3u((key), s6, s7);                                   \
        s6  = med3u((key), s5, s6);                                   \
        s5  = med3u((key), s4, s5);                                   \
        s4  = med3u((key), s3, s4);                                   \
        s3  = med3u((key), s2, s3);                                   \
        s2  = med3u((key), s1, s2);                                   \
        s1  = med3u((key), s0, s1);                                   \
        s0  = n0; }
    {
        const unsigned* kr = &keys_lds[(h * 32 + col) * 49];
#pragma unroll 8
        for (int c = 0; c < 48; c++) {
            unsigned key = kr[c];
            INSK(key);
        }
    }
#undef INSK

    unsigned r0, r1, r2;
    if      (wv == 0) { r0 = s0; r1 = s1;  r2 = s2;  }
    else if (wv == 1) { r0 = s3; r1 = s4;  r2 = s5;  }
    else if (wv == 2) { r0 = s6; r1 = s7;  r2 = s8;  }
    else              { r0 = s9; r1 = s10; r2 = s11; }

    // -------- Exact stable tail: ranks [3wv, 3wv+3), R5-verbatim body -----
    const double INITK = __hiloint2double(0x7F800000, 0);   // huge finite key
    double K0 = INITK, K1 = INITK, K2 = INITK;
#define INS3(kk) { if ((kk) < K2) {                                  \
        if ((kk) < K1) { K2 = K1;                                    \
            if ((kk) < K0) { K1 = K0; K0 = (kk); } else K1 = (kk);   \
        } else K2 = (kk); } }

#pragma unroll
    for (int r = 0; r < 3; r++) {
        const unsigned rr = (r == 0) ? r0 : ((r == 1) ? r1 : r2);
        const int bb = (int)(rr & 127u);
        const float4* Sb = S + bb * 32 + 4 * h;
        const int sbase = bb * 32 + 4 * h;
#pragma unroll
        for (int e = 0; e < 16; e++) {
            const int row = (e & 3) + 8 * (e >> 2);
            float4 s = Sb[row];
            float d = dist_exact(T, s);
            double kk = __hiloint2double(__float_as_int(d), sbase + row);
            INS3(kk);
        }
    }

    // merge lane-halves (disjoint row-sets of this wave's rank subset)
    double O0 = __shfl_xor(K0, 32);
    double O1 = __shfl_xor(K1, 32);
    double O2 = __shfl_xor(K2, 32);
    INS3(O0); INS3(O1); INS3(O2);
#undef INS3

    if (h == 0) {
        double* tw = &tails_lds[col * 13 + wv * 3];
        tw[0] = K0; tw[1] = K1; tw[2] = K2;
    }
    __syncthreads();

    // -------- Phase C: fold 4 waves' partial top-3 -> weights + idx3 ------
    if (tid < 32) {
        double M0 = INITK, M1 = INITK, M2 = INITK;
#define INSM(kk) { if ((kk) < M2) {                                  \
        if ((kk) < M1) { M2 = M1;                                    \
            if ((kk) < M0) { M1 = M0; M0 = (kk); } else M1 = (kk);   \
        } else M2 = (kk); } }
#pragma unroll
        for (int p = 0; p < 12; p++) {
            double kk = tails_lds[tid * 13 + p];
            INSM(kk);
        }
#undef INSM
        const int t = tgtg * 32 + tid;
        float d0 = __int_as_float(__double2hiint(M0));
        float d1 = __int_as_float(__double2hiint(M1));
        float d2 = __int_as_float(__double2hiint(M2));
        float w0 = 1.0f / __fadd_rn(d0, 1e-8f);
        float w1 = 1.0f / __fadd_rn(d1, 1e-8f);
        float w2 = 1.0f / __fadd_rn(d2, 1e-8f);
        float ws = __fadd_rn(__fadd_rn(w0, w1), w2);
        w3[(size_t)t * 3 + 0] = w0 / ws;
        w3[(size_t)t * 3 + 1] = w1 / ws;
        w3[(size_t)t * 3 + 2] = w2 / ws;
        idx3[(size_t)t * 3 + 0] = __double2loint(M0);
        idx3[(size_t)t * 3 + 1] = __double2loint(M1);
        idx3[(size_t)t * 3 + 2] = __double2loint(M2);
    }
}

// ---------------------------------------------------------------------------
// bf16 MFMA GEMM + BN + ReLU (verified). Used for feats1.
// ---------------------------------------------------------------------------
__global__ __launch_bounds__(256) void gemm_bf16_bn_relu(
    const unsigned short* __restrict__ Ap,
    const unsigned short* __restrict__ Bp,
    const float* __restrict__ bias,
    const float* __restrict__ gamma,
    const float* __restrict__ beta,
    const float* __restrict__ mean,
    const float* __restrict__ var,
    float* __restrict__ out, int M, int K)
{
    __shared__ __align__(16) unsigned short As[4096];
    __shared__ __align__(16) unsigned short Bs[4096];

    const int tid  = threadIdx.x;
    const int w    = tid >> 6;
    const int lane = tid & 63;
    const int q    = lane >> 4;
    const int rl   = lane & 15;
    const int wm   = w >> 1, wn = w & 1;
    const int bn   = blockIdx.x, bm = blockIdx.y;
    const int nslab = K >> 5;

    f32x4 acc[4][4];
#pragma unroll
    for (int i = 0; i < 4; i++)
#pragma unroll
        for (int j = 0; j < 4; j++) acc[i][j] = (f32x4){0.f, 0.f, 0.f, 0.f};

    const unsigned short* Ab = Ap + (size_t)bm * nslab * 4096;
    const unsigned short* Bb = Bp + (size_t)bn * nslab * 4096;
    const int c0 = 2 * w;
    const int l8 = lane * 8;

    int aidx[4], bidx[4];
#pragma unroll
    for (int i = 0; i < 4; i++) {
        int rr = wm * 64 + i * 16 + rl;
        aidx[i] = rr * 32 + ((q + (rr >> 1)) & 3) * 8;
        int nn = wn * 64 + i * 16 + rl;
        bidx[i] = nn * 32 + ((q + (nn >> 1)) & 3) * 8;
    }

    for (int s = 0; s < nslab; s++) {
        __syncthreads();
        const unsigned short* a = Ab + (size_t)s * 4096;
        const unsigned short* b = Bb + (size_t)s * 4096;
        gld_lds16(a + (c0 + 0) * 512 + l8, &As[(c0 + 0) * 512 + l8]);
        gld_lds16(a + (c0 + 1) * 512 + l8, &As[(c0 + 1) * 512 + l8]);
        gld_lds16(b + (c0 + 0) * 512 + l8, &Bs[(c0 + 0) * 512 + l8]);
        gld_lds16(b + (c0 + 1) * 512 + l8, &Bs[(c0 + 1) * 512 + l8]);
        __syncthreads();

        bf16x8 af[4], bf[4];
#pragma unroll
        for (int i = 0; i < 4; i++) af[i] = *(const bf16x8*)&As[aidx[i]];
#pragma unroll
        for (int j = 0; j < 4; j++) bf[j] = *(const bf16x8*)&Bs[bidx[j]];
#pragma unroll
        for (int i = 0; i < 4; i++)
#pragma unroll
            for (int j = 0; j < 4; j++)
                acc[i][j] = __builtin_amdgcn_mfma_f32_16x16x32_bf16(
                    af[i], bf[j], acc[i][j], 0, 0, 0);
    }

    const int gm0 = bm * 128 + wm * 64;
    const int gn0 = bn * 128 + wn * 64;
#pragma unroll
    for (int j = 0; j < 4; j++) {
        int n = gn0 + j * 16 + rl;
        float sc = gamma[n] / sqrtf(var[n] + EPS_BN);
        float sh = beta[n] + (bias[n] - mean[n]) * sc;
#pragma unroll
        for (int i = 0; i < 4; i++) {
            int m0 = gm0 + i * 16 + q * 4;
#pragma unroll
            for (int t = 0; t < 4; t++) {
                float v = fmaxf(acc[i][j][t] * sc + sh, 0.f);
                out[(size_t)(m0 + t) * 256 + n] = v;
            }
        }
    }
}

// ---------------------------------------------------------------------------
// GEMM2 + BN + ReLU + fused 3-NN interpolation add:
//   out[m][n] = relu(BN(A2@W2^T)) + sum_k w3[m][k] * feats1[b(m), idx3[m][k]][n]
// ---------------------------------------------------------------------------
__global__ __launch_bounds__(256) void gemm2_interp(
    const unsigned short* __restrict__ Ap,
    const unsigned short* __restrict__ Bp,
    const float* __restrict__ bias,
    const float* __restrict__ gamma,
    const float* __restrict__ beta,
    const float* __restrict__ mean,
    const float* __restrict__ var,
    const float* __restrict__ feats1,   // [4*4096][256]
    const float* __restrict__ w3,       // [65536][3]
    const int*   __restrict__ idx3,     // [65536][3] (within-batch indices)
    float* __restrict__ out)
{
    __shared__ __align__(16) unsigned short As[4096];
    __shared__ __align__(16) unsigned short Bs[4096];

    const int tid  = threadIdx.x;
    const int w    = tid >> 6;
    const int lane = tid & 63;
    const int q    = lane >> 4;
    const int rl   = lane & 15;
    const int wm   = w >> 1, wn = w & 1;
    const int bn   = blockIdx.x, bm = blockIdx.y;
    const int nslab = 8;                 // K = 256

    f32x4 acc[4][4];
#pragma unroll
    for (int i = 0; i < 4; i++)
#pragma unroll
        for (int j = 0; j < 4; j++) acc[i][j] = (f32x4){0.f, 0.f, 0.f, 0.f};

    const unsigned short* Ab = Ap + (size_t)bm * nslab * 4096;
    const unsigned short* Bb = Bp + (size_t)bn * nslab * 4096;
    const int c0 = 2 * w;
    const int l8 = lane * 8;

    int aidx[4], bidx[4];
#pragma unroll
    for (int i = 0; i < 4; i++) {
        int rr = wm * 64 + i * 16 + rl;
        aidx[i] = rr * 32 + ((q + (rr >> 1)) & 3) * 8;
        int nn = wn * 64 + i * 16 + rl;
        bidx[i] = nn * 32 + ((q + (nn >> 1)) & 3) * 8;
    }

    for (int s = 0; s < nslab; s++) {
        __syncthreads();
        const unsigned short* a = Ab + (size_t)s * 4096;
        const unsigned short* b = Bb + (size_t)s * 4096;
        gld_lds16(a + (c0 + 0) * 512 + l8, &As[(c0 + 0) * 512 + l8]);
        gld_lds16(a + (c0 + 1) * 512 + l8, &As[(c0 + 1) * 512 + l8]);
        gld_lds16(b + (c0 + 0) * 512 + l8, &Bs[(c0 + 0) * 512 + l8]);
        gld_lds16(b + (c0 + 1) * 512 + l8, &Bs[(c0 + 1) * 512 + l8]);
        __syncthreads();

        bf16x8 af[4], bf[4];
#pragma unroll
        for (int i = 0; i < 4; i++) af[i] = *(const bf16x8*)&As[aidx[i]];
#pragma unroll
        for (int j = 0; j < 4; j++) bf[j] = *(const bf16x8*)&Bs[bidx[j]];
#pragma unroll
        for (int i = 0; i < 4; i++)
#pragma unroll
            for (int j = 0; j < 4; j++)
                acc[i][j] = __builtin_amdgcn_mfma_f32_16x16x32_bf16(
                    af[i], bf[j], acc[i][j], 0, 0, 0);
    }

    const int gm0 = bm * 128 + wm * 64;
    const int gn0 = bn * 128 + wn * 64;
    float scj[4], shj[4];
    int nj[4];
#pragma unroll
    for (int j = 0; j < 4; j++) {
        int n = gn0 + j * 16 + rl;
        nj[j] = n;
        float sc = gamma[n] / sqrtf(var[n] + EPS_BN);
        scj[j] = sc;
        shj[j] = beta[n] + (bias[n] - mean[n]) * sc;
    }

#pragma unroll
    for (int i = 0; i < 4; i++) {
#pragma unroll
        for (int t = 0; t < 4; t++) {
            const int m = gm0 + i * 16 + q * 4 + t;      // global target row
            const int bb = m >> 14;                      // batch
            const int j0 = idx3[(size_t)m * 3 + 0];
            const int j1 = idx3[(size_t)m * 3 + 1];
            const int j2 = idx3[(size_t)m * 3 + 2];
            const float u0 = w3[(size_t)m * 3 + 0];
            const float u1 = w3[(size_t)m * 3 + 1];
            const float u2 = w3[(size_t)m * 3 + 2];
            const float* f0 = feats1 + ((size_t)(bb * 4096 + j0)) * 256;
            const float* f1 = feats1 + ((size_t)(bb * 4096 + j1)) * 256;
            const float* f2 = feats1 + ((size_t)(bb * 4096 + j2)) * 256;
#pragma unroll
            for (int j = 0; j < 4; j++) {
                const int n = nj[j];
                float v = fmaxf(acc[i][j][t] * scj[j] + shj[j], 0.f);
                v += u0 * f0[n] + u1 * f1[n] + u2 * f2[n];
                out[(size_t)m * 256 + n] = v;
            }
        }
    }
}

extern "C" void kernel_launch(void* const* d_in, const int* in_sizes, int n_in,
                              void* d_out, int out_size, void* d_ws, size_t ws_size,
                              hipStream_t stream) {
    const float* xyz1    = (const float*)d_in[0];
    const float* points1 = (const float*)d_in[1];
    const float* xyz2    = (const float*)d_in[2];
    const float* points2 = (const float*)d_in[3];
    const float* W1  = (const float*)d_in[4];
    const float* b1  = (const float*)d_in[5];
    const float* g1  = (const float*)d_in[6];
    const float* be1 = (const float*)d_in[7];
    const float* m1  = (const float*)d_in[8];
    const float* v1  = (const float*)d_in[9];
    const float* W2  = (const float*)d_in[10];
    const float* b2  = (const float*)d_in[11];
    const float* g2  = (const float*)d_in[12];
    const float* be2 = (const float*)d_in[13];
    const float* m2  = (const float*)d_in[14];
    const float* v2  = (const float*)d_in[15];

    const size_t MB = 1u << 20;
    char* ws = (char*)d_ws;
    // srcpk/tgtpk live in [0,16)MB, dead before gemm1 writes feats1 there.
    float*          feats1 = (float*)(ws);                       // 16 MB
    _Float16*       srcpk  = (_Float16*)(ws);                    // 512 KB
    _Float16*       tgtpk  = (_Float16*)(ws + 1 * MB);           // 2 MB
    unsigned short* A1p    = (unsigned short*)(ws + 16 * MB);    // 16 MB
    unsigned short* A2p    = (unsigned short*)(ws + 32 * MB);    // 32 MB
    unsigned short* W1p    = (unsigned short*)(ws + 64 * MB);    // 0.5 MB
    unsigned short* W2p    = (unsigned short*)(ws + 64 * MB + 512 * 1024);
    float4*         sxyz1  = (float4*)(ws + 65 * MB);            // 256 KB
    float4*         txyz2  = (float4*)(ws + 66 * MB);            // 1 MB
    float*          w3     = (float*)(ws + 67 * MB);             // 0.75 MB
    int*            idx3   = (int*)(ws + 68 * MB);               // 0.75 MB
    float* outp = (float*)d_out;

    dim3 blk(256);
    // 1) all packing/conversion in one dispatch
    prep_all<<<12704, blk, 0, stream>>>(points1, points2, W1, W2,
                                        A1p, A2p, W1p, W2p,
                                        xyz1, xyz2, sxyz1, srcpk, tgtpk, txyz2);
    // 2) neighbor selection: fused partitioned scan + merged exact tail
    knn_fused<<<2048, blk, 0, stream>>>(sxyz1, srcpk, tgtpk, txyz2, w3, idx3);
    // 3) feats1 = relu(BN(points1 @ W1^T))  (clobbers srcpk/tgtpk — dead)
    gemm_bf16_bn_relu<<<dim3(2, 128), blk, 0, stream>>>(A1p, W1p, b1, g1, be1, m1, v1,
                                                        feats1, 16384, 512);
    // 4) out = relu(BN(points2 @ W2^T)) + interp3(xyz2 <- xyz1, feats1)
    gemm2_interp<<<dim3(2, 512), blk, 0, stream>>>(A2p, W2p, b2, g2, be2, m2, v2,
                                                   feats1, w3, idx3, outp);
}